// Round 1
// baseline (1039.201 us; speedup 1.0000x reference)
//
#include <hip/hip_runtime.h>

#define N_NODES 100000
#define N_EDGES 3200000
#define N_GRAPHS 1000
#define IN_DIM 10
#define HIDDEN 64

// ---------------- degree histogram ----------------
__global__ void k_deg(const int* __restrict__ col, int* __restrict__ deg) {
    int e = blockIdx.x * blockDim.x + threadIdx.x;
    if (e < N_EDGES) atomicAdd(&deg[col[e]], 1);
}

// ---------------- hierarchical exclusive scan (offsets) ----------------
__global__ __launch_bounds__(1024) void k_scan_block(const int* __restrict__ deg,
                                                     int* __restrict__ offs,
                                                     int* __restrict__ bsums) {
    __shared__ int s[1024];
    int t = threadIdx.x;
    int i = blockIdx.x * 1024 + t;
    int v = (i < N_NODES) ? deg[i] : 0;
    s[t] = v;
    __syncthreads();
    for (int d = 1; d < 1024; d <<= 1) {
        int x = (t >= d) ? s[t - d] : 0;
        __syncthreads();
        s[t] += x;
        __syncthreads();
    }
    if (i < N_NODES) offs[i] = s[t] - v;  // block-local exclusive
    if (t == 1023) bsums[blockIdx.x] = s[t];
}

__global__ __launch_bounds__(128) void k_scan_top(int* __restrict__ bsums, int nb) {
    __shared__ int s[128];
    int t = threadIdx.x;
    int v = (t < nb) ? bsums[t] : 0;
    s[t] = v;
    __syncthreads();
    for (int d = 1; d < 128; d <<= 1) {
        int x = (t >= d) ? s[t - d] : 0;
        __syncthreads();
        s[t] += x;
        __syncthreads();
    }
    if (t < nb) bsums[t] = s[t] - v;  // exclusive
}

__global__ __launch_bounds__(1024) void k_scan_add(int* __restrict__ offs,
                                                   const int* __restrict__ bsums) {
    int i = blockIdx.x * 1024 + threadIdx.x;
    if (i < N_NODES) offs[i] += bsums[blockIdx.x];
}

// ---------------- dinv ----------------
__global__ void k_dinv(const int* __restrict__ deg, float* __restrict__ dinv) {
    int n = blockIdx.x * blockDim.x + threadIdx.x;
    if (n < N_NODES) {
        int d = deg[n];
        dinv[n] = (d > 0) ? rsqrtf((float)d) : 0.f;
    }
}

// ---------------- CSR fill (bucket by target col) ----------------
__global__ void k_fill(const int* __restrict__ row, const int* __restrict__ col,
                       const int* __restrict__ offs, int* __restrict__ cursor,
                       int* __restrict__ csr_src) {
    int e = blockIdx.x * blockDim.x + threadIdx.x;
    if (e < N_EDGES) {
        int d = col[e];
        int p = atomicAdd(&cursor[d], 1);
        csr_src[offs[d] + p] = row[e];
    }
}

// ---------------- layer 1: aggregate x (10 dims) then @W1+b1, relu ----------------
__global__ __launch_bounds__(256) void k_layer1(const float* __restrict__ x,
                                                const float* __restrict__ dinv,
                                                const int* __restrict__ offs,
                                                const int* __restrict__ deg,
                                                const int* __restrict__ csr_src,
                                                const float* __restrict__ W1,
                                                const float* __restrict__ b1,
                                                float* __restrict__ h1) {
    int wid = (blockIdx.x * blockDim.x + threadIdx.x) >> 6;
    int lane = threadIdx.x & 63;
    if (wid >= N_NODES) return;
    int n = wid;
    int start = offs[n], dn = deg[n];
    float a = 0.f;
    for (int base = 0; base < dn; base += 64) {
        int nb = min(64, dn - base);
        int src = 0;
        float w = 0.f;
        if (lane < nb) {
            src = csr_src[start + base + lane];
            w = dinv[src];
        }
        for (int j = 0; j < nb; ++j) {
            int s = __shfl(src, j);
            float ww = __shfl(w, j);
            if (lane < IN_DIM) a += x[s * IN_DIM + lane] * ww;
        }
    }
    a *= dinv[n];
    float acc = b1[lane];
#pragma unroll
    for (int k = 0; k < IN_DIM; ++k) {
        acc += __shfl(a, k) * W1[k * HIDDEN + lane];
    }
    h1[n * HIDDEN + lane] = fmaxf(acc, 0.f);
}

// ---------------- layer 2: aggregate h1 (64 dims) then @W2+b2, relu ----------------
__global__ __launch_bounds__(256) void k_layer2(const float* __restrict__ hin,
                                                const float* __restrict__ dinv,
                                                const int* __restrict__ offs,
                                                const int* __restrict__ deg,
                                                const int* __restrict__ csr_src,
                                                const float* __restrict__ W,
                                                const float* __restrict__ b,
                                                float* __restrict__ hout) {
    __shared__ float sW[HIDDEN * HIDDEN];
    for (int i = threadIdx.x; i < HIDDEN * HIDDEN; i += blockDim.x) sW[i] = W[i];
    __syncthreads();
    int wid = (blockIdx.x * blockDim.x + threadIdx.x) >> 6;
    int lane = threadIdx.x & 63;
    if (wid >= N_NODES) return;
    int n = wid;
    int start = offs[n], dn = deg[n];
    float a = 0.f;
    for (int base = 0; base < dn; base += 64) {
        int nb = min(64, dn - base);
        int src = 0;
        float w = 0.f;
        if (lane < nb) {
            src = csr_src[start + base + lane];
            w = dinv[src];
        }
        for (int j = 0; j < nb; ++j) {
            int s = __shfl(src, j);
            float ww = __shfl(w, j);
            a += hin[s * HIDDEN + lane] * ww;
        }
    }
    a *= dinv[n];
    float acc = b[lane];
    for (int k = 0; k < HIDDEN; ++k) {
        acc += __shfl(a, k) * sW[k * HIDDEN + lane];
    }
    hout[n * HIDDEN + lane] = fmaxf(acc, 0.f);
}

// ---------------- layer 3: aggregate h2, pool into graph accumulator ----------------
__global__ __launch_bounds__(256) void k_layer3(const float* __restrict__ hin,
                                                const float* __restrict__ dinv,
                                                const int* __restrict__ offs,
                                                const int* __restrict__ deg,
                                                const int* __restrict__ csr_src,
                                                const int* __restrict__ batch,
                                                float* __restrict__ gpre,
                                                int* __restrict__ gcnt) {
    int wid = (blockIdx.x * blockDim.x + threadIdx.x) >> 6;
    int lane = threadIdx.x & 63;
    if (wid >= N_NODES) return;
    int n = wid;
    int start = offs[n], dn = deg[n];
    float a = 0.f;
    for (int base = 0; base < dn; base += 64) {
        int nb = min(64, dn - base);
        int src = 0;
        float w = 0.f;
        if (lane < nb) {
            src = csr_src[start + base + lane];
            w = dinv[src];
        }
        for (int j = 0; j < nb; ++j) {
            int s = __shfl(src, j);
            float ww = __shfl(w, j);
            a += hin[s * HIDDEN + lane] * ww;
        }
    }
    a *= dinv[n];
    int g = batch[n];
    atomicAdd(&gpre[g * HIDDEN + lane], a);
    if (lane == 0) atomicAdd(&gcnt[g], 1);
}

// ---------------- final: pooled @ W3 + cnt*b3, @ Wl + bl, softmax ----------------
__global__ __launch_bounds__(256) void k_final(const float* __restrict__ gpre,
                                               const int* __restrict__ gcnt,
                                               const float* __restrict__ W3,
                                               const float* __restrict__ b3,
                                               const float* __restrict__ Wl,
                                               const float* __restrict__ bl,
                                               float* __restrict__ out) {
    int wid = (blockIdx.x * blockDim.x + threadIdx.x) >> 6;
    int lane = threadIdx.x & 63;
    if (wid >= N_GRAPHS) return;
    float pre = gpre[wid * HIDDEN + lane];
    float cnt = (float)gcnt[wid];
    float emb = cnt * b3[lane];
    for (int k = 0; k < HIDDEN; ++k) {
        emb += __shfl(pre, k) * W3[k * HIDDEN + lane];
    }
    float p0 = emb * Wl[lane * 2 + 0];
    float p1 = emb * Wl[lane * 2 + 1];
    for (int d = 32; d > 0; d >>= 1) {
        p0 += __shfl_xor(p0, d);
        p1 += __shfl_xor(p1, d);
    }
    if (lane == 0) {
        float l0 = p0 + bl[0], l1 = p1 + bl[1];
        float m = fmaxf(l0, l1);
        float e0 = __expf(l0 - m), e1 = __expf(l1 - m);
        float inv = 1.f / (e0 + e1);
        out[wid * 2 + 0] = e0 * inv;
        out[wid * 2 + 1] = e1 * inv;
    }
}

extern "C" void kernel_launch(void* const* d_in, const int* in_sizes, int n_in,
                              void* d_out, int out_size, void* d_ws, size_t ws_size,
                              hipStream_t stream) {
    const float* x = (const float*)d_in[0];
    const int* edge = (const int*)d_in[1];  // [2, E] flattened: row = edge[0:E], col = edge[E:2E]
    const int* batch = (const int*)d_in[2];
    const float* W1 = (const float*)d_in[3];
    const float* b1 = (const float*)d_in[4];
    const float* W2 = (const float*)d_in[5];
    const float* b2 = (const float*)d_in[6];
    const float* W3 = (const float*)d_in[7];
    const float* b3 = (const float*)d_in[8];
    const float* Wl = (const float*)d_in[9];
    const float* bl = (const float*)d_in[10];
    float* out = (float*)d_out;

    const int* row = edge;
    const int* col = edge + N_EDGES;

    // workspace carve-up (256B aligned)
    char* ws = (char*)d_ws;
    size_t off = 0;
    auto alloc = [&](size_t bytes) -> void* {
        void* p = ws + off;
        off = (off + bytes + 255) & ~(size_t)255;
        return p;
    };
    int* deg = (int*)alloc((size_t)N_NODES * 4);
    int* offs = (int*)alloc((size_t)N_NODES * 4);
    int* bsums = (int*)alloc(128 * 4);
    int* cursor = (int*)alloc((size_t)N_NODES * 4);
    float* dinv = (float*)alloc((size_t)N_NODES * 4);
    int* csr_src = (int*)alloc((size_t)N_EDGES * 4);
    float* h1 = (float*)alloc((size_t)N_NODES * HIDDEN * 4);
    float* h2 = (float*)alloc((size_t)N_NODES * HIDDEN * 4);
    float* gpre = (float*)alloc((size_t)N_GRAPHS * HIDDEN * 4);
    int* gcnt = (int*)alloc((size_t)N_GRAPHS * 4);

    hipMemsetAsync(deg, 0, (size_t)N_NODES * 4, stream);
    hipMemsetAsync(cursor, 0, (size_t)N_NODES * 4, stream);
    hipMemsetAsync(gpre, 0, (size_t)N_GRAPHS * HIDDEN * 4, stream);
    hipMemsetAsync(gcnt, 0, (size_t)N_GRAPHS * 4, stream);

    const int EB = (N_EDGES + 255) / 256;
    const int NB1024 = (N_NODES + 1023) / 1024;  // 98

    k_deg<<<EB, 256, 0, stream>>>(col, deg);
    k_scan_block<<<NB1024, 1024, 0, stream>>>(deg, offs, bsums);
    k_scan_top<<<1, 128, 0, stream>>>(bsums, NB1024);
    k_scan_add<<<NB1024, 1024, 0, stream>>>(offs, bsums);
    k_dinv<<<(N_NODES + 255) / 256, 256, 0, stream>>>(deg, dinv);
    k_fill<<<EB, 256, 0, stream>>>(row, col, offs, cursor, csr_src);

    const int WB = (N_NODES * 64 + 255) / 256;  // one wave per node
    k_layer1<<<WB, 256, 0, stream>>>(x, dinv, offs, deg, csr_src, W1, b1, h1);
    k_layer2<<<WB, 256, 0, stream>>>(h1, dinv, offs, deg, csr_src, W2, b2, h2);
    k_layer3<<<WB, 256, 0, stream>>>(h2, dinv, offs, deg, csr_src, batch, gpre, gcnt);
    k_final<<<(N_GRAPHS * 64 + 255) / 256, 256, 0, stream>>>(gpre, gcnt, W3, b3, Wl, bl, out);
}

// Round 2
// 815.542 us; speedup vs baseline: 1.2742x; 1.2742x over previous
//
#include <hip/hip_runtime.h>

#define N_NODES 100000
#define N_EDGES 3200000
#define N_GRAPHS 1000
#define IN_DIM 10
#define HIDDEN 64

// ---------------- degree histogram ----------------
__global__ void k_deg(const int* __restrict__ col, int* __restrict__ deg) {
    int e = blockIdx.x * blockDim.x + threadIdx.x;
    if (e < N_EDGES) atomicAdd(&deg[col[e]], 1);
}

// ---------------- hierarchical exclusive scan (offsets) ----------------
__global__ __launch_bounds__(1024) void k_scan_block(const int* __restrict__ deg,
                                                     int* __restrict__ offs,
                                                     int* __restrict__ bsums) {
    __shared__ int s[1024];
    int t = threadIdx.x;
    int i = blockIdx.x * 1024 + t;
    int v = (i < N_NODES) ? deg[i] : 0;
    s[t] = v;
    __syncthreads();
    for (int d = 1; d < 1024; d <<= 1) {
        int x = (t >= d) ? s[t - d] : 0;
        __syncthreads();
        s[t] += x;
        __syncthreads();
    }
    if (i < N_NODES) offs[i] = s[t] - v;  // block-local exclusive
    if (t == 1023) bsums[blockIdx.x] = s[t];
}

__global__ __launch_bounds__(128) void k_scan_top(int* __restrict__ bsums, int nb) {
    __shared__ int s[128];
    int t = threadIdx.x;
    int v = (t < nb) ? bsums[t] : 0;
    s[t] = v;
    __syncthreads();
    for (int d = 1; d < 128; d <<= 1) {
        int x = (t >= d) ? s[t - d] : 0;
        __syncthreads();
        s[t] += x;
        __syncthreads();
    }
    if (t < nb) bsums[t] = s[t] - v;  // exclusive
}

__global__ __launch_bounds__(1024) void k_scan_add(int* __restrict__ offs,
                                                   const int* __restrict__ bsums) {
    int i = blockIdx.x * 1024 + threadIdx.x;
    if (i < N_NODES) offs[i] += bsums[blockIdx.x];
}

// ---------------- dinv ----------------
__global__ void k_dinv(const int* __restrict__ deg, float* __restrict__ dinv) {
    int n = blockIdx.x * blockDim.x + threadIdx.x;
    if (n < N_NODES) {
        int d = deg[n];
        dinv[n] = (d > 0) ? rsqrtf((float)d) : 0.f;
    }
}

// ---------------- CSR fill (bucket by target col) ----------------
__global__ void k_fill(const int* __restrict__ row, const int* __restrict__ col,
                       const int* __restrict__ offs, int* __restrict__ cursor,
                       int* __restrict__ csr_src) {
    int e = blockIdx.x * blockDim.x + threadIdx.x;
    if (e < N_EDGES) {
        int d = col[e];
        int p = atomicAdd(&cursor[d], 1);
        csr_src[offs[d] + p] = row[e];
    }
}

// Batched gather-accumulate core: 8 independent loads in flight per step.
// hin is [N, HIDDEN]; each lane owns feature `lane`.
__device__ __forceinline__ float agg64(const float* __restrict__ hin,
                                       const float* __restrict__ dinv,
                                       const int* __restrict__ csr_src,
                                       int start, int dn, int lane) {
    float a = 0.f;
    for (int base = 0; base < dn; base += 64) {
        int nb = min(64, dn - base);
        int src = 0;
        float w = 0.f;
        if (lane < nb) {
            src = csr_src[start + base + lane];
            w = dinv[src];
        }
        int j = 0;
        for (; j + 8 <= nb; j += 8) {
            float v0, v1, v2, v3, v4, v5, v6, v7;
            float w0, w1, w2, w3, w4, w5, w6, w7;
            int s0 = __shfl(src, j + 0); w0 = __shfl(w, j + 0);
            int s1 = __shfl(src, j + 1); w1 = __shfl(w, j + 1);
            int s2 = __shfl(src, j + 2); w2 = __shfl(w, j + 2);
            int s3 = __shfl(src, j + 3); w3 = __shfl(w, j + 3);
            int s4 = __shfl(src, j + 4); w4 = __shfl(w, j + 4);
            int s5 = __shfl(src, j + 5); w5 = __shfl(w, j + 5);
            int s6 = __shfl(src, j + 6); w6 = __shfl(w, j + 6);
            int s7 = __shfl(src, j + 7); w7 = __shfl(w, j + 7);
            v0 = hin[s0 * HIDDEN + lane];
            v1 = hin[s1 * HIDDEN + lane];
            v2 = hin[s2 * HIDDEN + lane];
            v3 = hin[s3 * HIDDEN + lane];
            v4 = hin[s4 * HIDDEN + lane];
            v5 = hin[s5 * HIDDEN + lane];
            v6 = hin[s6 * HIDDEN + lane];
            v7 = hin[s7 * HIDDEN + lane];
            a += v0 * w0; a += v1 * w1; a += v2 * w2; a += v3 * w3;
            a += v4 * w4; a += v5 * w5; a += v6 * w6; a += v7 * w7;
        }
        for (; j < nb; ++j) {
            int s = __shfl(src, j);
            float ww = __shfl(w, j);
            a += hin[s * HIDDEN + lane] * ww;
        }
    }
    return a;
}

// ---------------- layer 1: aggregate x (10 dims) then @W1+b1, relu ----------------
__global__ __launch_bounds__(256) void k_layer1(const float* __restrict__ x,
                                                const float* __restrict__ dinv,
                                                const int* __restrict__ offs,
                                                const int* __restrict__ deg,
                                                const int* __restrict__ csr_src,
                                                const float* __restrict__ W1,
                                                const float* __restrict__ b1,
                                                float* __restrict__ h1) {
    int wid = (blockIdx.x * blockDim.x + threadIdx.x) >> 6;
    int lane = threadIdx.x & 63;
    if (wid >= N_NODES) return;
    int n = wid;
    int start = offs[n], dn = deg[n];
    float a = 0.f;
    for (int base = 0; base < dn; base += 64) {
        int nb = min(64, dn - base);
        int src = 0;
        float w = 0.f;
        if (lane < nb) {
            src = csr_src[start + base + lane];
            w = dinv[src];
        }
        int j = 0;
        for (; j + 8 <= nb; j += 8) {
            float v0 = 0, v1 = 0, v2 = 0, v3 = 0, v4 = 0, v5 = 0, v6 = 0, v7 = 0;
            int s0 = __shfl(src, j + 0); float w0 = __shfl(w, j + 0);
            int s1 = __shfl(src, j + 1); float w1 = __shfl(w, j + 1);
            int s2 = __shfl(src, j + 2); float w2 = __shfl(w, j + 2);
            int s3 = __shfl(src, j + 3); float w3 = __shfl(w, j + 3);
            int s4 = __shfl(src, j + 4); float w4 = __shfl(w, j + 4);
            int s5 = __shfl(src, j + 5); float w5 = __shfl(w, j + 5);
            int s6 = __shfl(src, j + 6); float w6 = __shfl(w, j + 6);
            int s7 = __shfl(src, j + 7); float w7 = __shfl(w, j + 7);
            if (lane < IN_DIM) {
                v0 = x[s0 * IN_DIM + lane];
                v1 = x[s1 * IN_DIM + lane];
                v2 = x[s2 * IN_DIM + lane];
                v3 = x[s3 * IN_DIM + lane];
                v4 = x[s4 * IN_DIM + lane];
                v5 = x[s5 * IN_DIM + lane];
                v6 = x[s6 * IN_DIM + lane];
                v7 = x[s7 * IN_DIM + lane];
            }
            a += v0 * w0; a += v1 * w1; a += v2 * w2; a += v3 * w3;
            a += v4 * w4; a += v5 * w5; a += v6 * w6; a += v7 * w7;
        }
        for (; j < nb; ++j) {
            int s = __shfl(src, j);
            float ww = __shfl(w, j);
            if (lane < IN_DIM) a += x[s * IN_DIM + lane] * ww;
        }
    }
    a *= dinv[n];
    float acc = b1[lane];
#pragma unroll
    for (int k = 0; k < IN_DIM; ++k) {
        acc += __shfl(a, k) * W1[k * HIDDEN + lane];
    }
    h1[n * HIDDEN + lane] = fmaxf(acc, 0.f);
}

// ---------------- layer 2: aggregate h1 (64 dims) then @W2+b2, relu ----------------
__global__ __launch_bounds__(256) void k_layer2(const float* __restrict__ hin,
                                                const float* __restrict__ dinv,
                                                const int* __restrict__ offs,
                                                const int* __restrict__ deg,
                                                const int* __restrict__ csr_src,
                                                const float* __restrict__ W,
                                                const float* __restrict__ b,
                                                float* __restrict__ hout) {
    __shared__ float sW[HIDDEN * HIDDEN];
    for (int i = threadIdx.x; i < HIDDEN * HIDDEN; i += blockDim.x) sW[i] = W[i];
    __syncthreads();
    int wid = (blockIdx.x * blockDim.x + threadIdx.x) >> 6;
    int lane = threadIdx.x & 63;
    if (wid >= N_NODES) return;
    int n = wid;
    float a = agg64(hin, dinv, csr_src, offs[n], deg[n], lane);
    a *= dinv[n];
    float acc = b[lane];
    for (int k = 0; k < HIDDEN; ++k) {
        acc += __shfl(a, k) * sW[k * HIDDEN + lane];
    }
    hout[n * HIDDEN + lane] = fmaxf(acc, 0.f);
}

// ---------------- layer 3: aggregate h2, pool into graph accumulator ----------------
__global__ __launch_bounds__(256) void k_layer3(const float* __restrict__ hin,
                                                const float* __restrict__ dinv,
                                                const int* __restrict__ offs,
                                                const int* __restrict__ deg,
                                                const int* __restrict__ csr_src,
                                                const int* __restrict__ batch,
                                                float* __restrict__ gpre,
                                                int* __restrict__ gcnt) {
    int wid = (blockIdx.x * blockDim.x + threadIdx.x) >> 6;
    int lane = threadIdx.x & 63;
    if (wid >= N_NODES) return;
    int n = wid;
    float a = agg64(hin, dinv, csr_src, offs[n], deg[n], lane);
    a *= dinv[n];
    int g = batch[n];
    atomicAdd(&gpre[g * HIDDEN + lane], a);
    if (lane == 0) atomicAdd(&gcnt[g], 1);
}

// ---------------- final: pooled @ W3 + cnt*b3, @ Wl + bl, softmax ----------------
__global__ __launch_bounds__(256) void k_final(const float* __restrict__ gpre,
                                               const int* __restrict__ gcnt,
                                               const float* __restrict__ W3,
                                               const float* __restrict__ b3,
                                               const float* __restrict__ Wl,
                                               const float* __restrict__ bl,
                                               float* __restrict__ out) {
    int wid = (blockIdx.x * blockDim.x + threadIdx.x) >> 6;
    int lane = threadIdx.x & 63;
    if (wid >= N_GRAPHS) return;
    float pre = gpre[wid * HIDDEN + lane];
    float cnt = (float)gcnt[wid];
    float emb = cnt * b3[lane];
    for (int k = 0; k < HIDDEN; ++k) {
        emb += __shfl(pre, k) * W3[k * HIDDEN + lane];
    }
    float p0 = emb * Wl[lane * 2 + 0];
    float p1 = emb * Wl[lane * 2 + 1];
    for (int d = 32; d > 0; d >>= 1) {
        p0 += __shfl_xor(p0, d);
        p1 += __shfl_xor(p1, d);
    }
    if (lane == 0) {
        float l0 = p0 + bl[0], l1 = p1 + bl[1];
        float m = fmaxf(l0, l1);
        float e0 = __expf(l0 - m), e1 = __expf(l1 - m);
        float inv = 1.f / (e0 + e1);
        out[wid * 2 + 0] = e0 * inv;
        out[wid * 2 + 1] = e1 * inv;
    }
}

extern "C" void kernel_launch(void* const* d_in, const int* in_sizes, int n_in,
                              void* d_out, int out_size, void* d_ws, size_t ws_size,
                              hipStream_t stream) {
    const float* x = (const float*)d_in[0];
    const int* edge = (const int*)d_in[1];  // [2, E] flattened: row = edge[0:E], col = edge[E:2E]
    const int* batch = (const int*)d_in[2];
    const float* W1 = (const float*)d_in[3];
    const float* b1 = (const float*)d_in[4];
    const float* W2 = (const float*)d_in[5];
    const float* b2 = (const float*)d_in[6];
    const float* W3 = (const float*)d_in[7];
    const float* b3 = (const float*)d_in[8];
    const float* Wl = (const float*)d_in[9];
    const float* bl = (const float*)d_in[10];
    float* out = (float*)d_out;

    const int* row = edge;
    const int* col = edge + N_EDGES;

    // workspace carve-up (256B aligned)
    char* ws = (char*)d_ws;
    size_t off = 0;
    auto alloc = [&](size_t bytes) -> void* {
        void* p = ws + off;
        off = (off + bytes + 255) & ~(size_t)255;
        return p;
    };
    int* deg = (int*)alloc((size_t)N_NODES * 4);
    int* offs = (int*)alloc((size_t)N_NODES * 4);
    int* bsums = (int*)alloc(128 * 4);
    int* cursor = (int*)alloc((size_t)N_NODES * 4);
    float* dinv = (float*)alloc((size_t)N_NODES * 4);
    int* csr_src = (int*)alloc((size_t)N_EDGES * 4);
    float* h1 = (float*)alloc((size_t)N_NODES * HIDDEN * 4);
    float* h2 = (float*)alloc((size_t)N_NODES * HIDDEN * 4);
    float* gpre = (float*)alloc((size_t)N_GRAPHS * HIDDEN * 4);
    int* gcnt = (int*)alloc((size_t)N_GRAPHS * 4);

    hipMemsetAsync(deg, 0, (size_t)N_NODES * 4, stream);
    hipMemsetAsync(cursor, 0, (size_t)N_NODES * 4, stream);
    hipMemsetAsync(gpre, 0, (size_t)N_GRAPHS * HIDDEN * 4, stream);
    hipMemsetAsync(gcnt, 0, (size_t)N_GRAPHS * 4, stream);

    const int EB = (N_EDGES + 255) / 256;
    const int NB1024 = (N_NODES + 1023) / 1024;  // 98

    k_deg<<<EB, 256, 0, stream>>>(col, deg);
    k_scan_block<<<NB1024, 1024, 0, stream>>>(deg, offs, bsums);
    k_scan_top<<<1, 128, 0, stream>>>(bsums, NB1024);
    k_scan_add<<<NB1024, 1024, 0, stream>>>(offs, bsums);
    k_dinv<<<(N_NODES + 255) / 256, 256, 0, stream>>>(deg, dinv);
    k_fill<<<EB, 256, 0, stream>>>(row, col, offs, cursor, csr_src);

    const int WB = (N_NODES * 64 + 255) / 256;  // one wave per node
    k_layer1<<<WB, 256, 0, stream>>>(x, dinv, offs, deg, csr_src, W1, b1, h1);
    k_layer2<<<WB, 256, 0, stream>>>(h1, dinv, offs, deg, csr_src, W2, b2, h2);
    k_layer3<<<WB, 256, 0, stream>>>(h2, dinv, offs, deg, csr_src, batch, gpre, gcnt);
    k_final<<<(N_GRAPHS * 64 + 255) / 256, 256, 0, stream>>>(gpre, gcnt, W3, b3, Wl, bl, out);
}

// Round 3
// 746.932 us; speedup vs baseline: 1.3913x; 1.0919x over previous
//
#include <hip/hip_runtime.h>

#define N_NODES 100000
#define N_EDGES 3200000
#define N_GRAPHS 1000
#define IN_DIM 10
#define HIDDEN 64

#define NRANGES 8
#define RANGE_SIZE ((N_NODES + NRANGES - 1) / NRANGES)  // 12500
#define CHUNK_EDGES 4096

// ---------------- degree histogram ----------------
__global__ void k_deg(const int* __restrict__ col, int* __restrict__ deg) {
    int e = blockIdx.x * blockDim.x + threadIdx.x;
    if (e < N_EDGES) atomicAdd(&deg[col[e]], 1);
}

// ---------------- hierarchical exclusive scan (offsets) ----------------
__global__ __launch_bounds__(1024) void k_scan_block(const int* __restrict__ deg,
                                                     int* __restrict__ offs,
                                                     int* __restrict__ bsums) {
    __shared__ int s[1024];
    int t = threadIdx.x;
    int i = blockIdx.x * 1024 + t;
    int v = (i < N_NODES) ? deg[i] : 0;
    s[t] = v;
    __syncthreads();
    for (int d = 1; d < 1024; d <<= 1) {
        int x = (t >= d) ? s[t - d] : 0;
        __syncthreads();
        s[t] += x;
        __syncthreads();
    }
    if (i < N_NODES) offs[i] = s[t] - v;  // block-local exclusive
    if (t == 1023) bsums[blockIdx.x] = s[t];
}

__global__ __launch_bounds__(128) void k_scan_top(int* __restrict__ bsums, int nb) {
    __shared__ int s[128];
    int t = threadIdx.x;
    int v = (t < nb) ? bsums[t] : 0;
    s[t] = v;
    __syncthreads();
    for (int d = 1; d < 128; d <<= 1) {
        int x = (t >= d) ? s[t - d] : 0;
        __syncthreads();
        s[t] += x;
        __syncthreads();
    }
    if (t < nb) bsums[t] = s[t] - v;  // exclusive
}

__global__ __launch_bounds__(1024) void k_scan_add(int* __restrict__ offs,
                                                   const int* __restrict__ bsums) {
    int i = blockIdx.x * 1024 + threadIdx.x;
    if (i < N_NODES) offs[i] += bsums[blockIdx.x];
}

// ---------------- dinv ----------------
__global__ void k_dinv(const int* __restrict__ deg, float* __restrict__ dinv) {
    int n = blockIdx.x * blockDim.x + threadIdx.x;
    if (n < N_NODES) {
        int d = deg[n];
        dinv[n] = (d > 0) ? rsqrtf((float)d) : 0.f;
    }
}

// ---------------- CSR fill, XCD-range-partitioned ----------------
// blockIdx&7 selects a target-node range (heuristically pinned to one XCD by
// round-robin dispatch); that XCD's cursor window (~50KB) and csr window
// (~1.6MB) stay L2-resident so csr lines fill completely before writeback.
__global__ __launch_bounds__(256) void k_fill(const int* __restrict__ row,
                                              const int* __restrict__ col,
                                              const int* __restrict__ offs,
                                              int* __restrict__ cursor,
                                              int* __restrict__ csr_src) {
    int range = blockIdx.x & (NRANGES - 1);
    int chunk = blockIdx.x >> 3;
    int lo = range * RANGE_SIZE;
    int hi = lo + RANGE_SIZE;
    int base = chunk * CHUNK_EDGES + threadIdx.x;
#pragma unroll
    for (int k = 0; k < CHUNK_EDGES / 256; ++k) {
        int e = base + k * 256;
        if (e < N_EDGES) {
            int c = col[e];
            int r = row[e];
            if (c >= lo && c < hi) {
                int p = atomicAdd(&cursor[c], 1);
                csr_src[offs[c] + p] = r;
            }
        }
    }
}

// Batched gather-accumulate core: 8 independent loads in flight per step.
// hin is [N, HIDDEN]; each lane owns feature `lane`.
__device__ __forceinline__ float agg64(const float* __restrict__ hin,
                                       const float* __restrict__ dinv,
                                       const int* __restrict__ csr_src,
                                       int start, int dn, int lane) {
    float a = 0.f;
    for (int base = 0; base < dn; base += 64) {
        int nb = min(64, dn - base);
        int src = 0;
        float w = 0.f;
        if (lane < nb) {
            src = csr_src[start + base + lane];
            w = dinv[src];
        }
        int j = 0;
        for (; j + 8 <= nb; j += 8) {
            float v0, v1, v2, v3, v4, v5, v6, v7;
            float w0, w1, w2, w3, w4, w5, w6, w7;
            int s0 = __shfl(src, j + 0); w0 = __shfl(w, j + 0);
            int s1 = __shfl(src, j + 1); w1 = __shfl(w, j + 1);
            int s2 = __shfl(src, j + 2); w2 = __shfl(w, j + 2);
            int s3 = __shfl(src, j + 3); w3 = __shfl(w, j + 3);
            int s4 = __shfl(src, j + 4); w4 = __shfl(w, j + 4);
            int s5 = __shfl(src, j + 5); w5 = __shfl(w, j + 5);
            int s6 = __shfl(src, j + 6); w6 = __shfl(w, j + 6);
            int s7 = __shfl(src, j + 7); w7 = __shfl(w, j + 7);
            v0 = hin[s0 * HIDDEN + lane];
            v1 = hin[s1 * HIDDEN + lane];
            v2 = hin[s2 * HIDDEN + lane];
            v3 = hin[s3 * HIDDEN + lane];
            v4 = hin[s4 * HIDDEN + lane];
            v5 = hin[s5 * HIDDEN + lane];
            v6 = hin[s6 * HIDDEN + lane];
            v7 = hin[s7 * HIDDEN + lane];
            a += v0 * w0; a += v1 * w1; a += v2 * w2; a += v3 * w3;
            a += v4 * w4; a += v5 * w5; a += v6 * w6; a += v7 * w7;
        }
        for (; j < nb; ++j) {
            int s = __shfl(src, j);
            float ww = __shfl(w, j);
            a += hin[s * HIDDEN + lane] * ww;
        }
    }
    return a;
}

// ---------------- layer 1: aggregate x (10 dims) then @W1+b1, relu ----------------
__global__ __launch_bounds__(256) void k_layer1(const float* __restrict__ x,
                                                const float* __restrict__ dinv,
                                                const int* __restrict__ offs,
                                                const int* __restrict__ deg,
                                                const int* __restrict__ csr_src,
                                                const float* __restrict__ W1,
                                                const float* __restrict__ b1,
                                                float* __restrict__ h1) {
    int wid = (blockIdx.x * blockDim.x + threadIdx.x) >> 6;
    int lane = threadIdx.x & 63;
    if (wid >= N_NODES) return;
    int n = wid;
    int start = offs[n], dn = deg[n];
    float a = 0.f;
    for (int base = 0; base < dn; base += 64) {
        int nb = min(64, dn - base);
        int src = 0;
        float w = 0.f;
        if (lane < nb) {
            src = csr_src[start + base + lane];
            w = dinv[src];
        }
        int j = 0;
        for (; j + 8 <= nb; j += 8) {
            float v0 = 0, v1 = 0, v2 = 0, v3 = 0, v4 = 0, v5 = 0, v6 = 0, v7 = 0;
            int s0 = __shfl(src, j + 0); float w0 = __shfl(w, j + 0);
            int s1 = __shfl(src, j + 1); float w1 = __shfl(w, j + 1);
            int s2 = __shfl(src, j + 2); float w2 = __shfl(w, j + 2);
            int s3 = __shfl(src, j + 3); float w3 = __shfl(w, j + 3);
            int s4 = __shfl(src, j + 4); float w4 = __shfl(w, j + 4);
            int s5 = __shfl(src, j + 5); float w5 = __shfl(w, j + 5);
            int s6 = __shfl(src, j + 6); float w6 = __shfl(w, j + 6);
            int s7 = __shfl(src, j + 7); float w7 = __shfl(w, j + 7);
            if (lane < IN_DIM) {
                v0 = x[s0 * IN_DIM + lane];
                v1 = x[s1 * IN_DIM + lane];
                v2 = x[s2 * IN_DIM + lane];
                v3 = x[s3 * IN_DIM + lane];
                v4 = x[s4 * IN_DIM + lane];
                v5 = x[s5 * IN_DIM + lane];
                v6 = x[s6 * IN_DIM + lane];
                v7 = x[s7 * IN_DIM + lane];
            }
            a += v0 * w0; a += v1 * w1; a += v2 * w2; a += v3 * w3;
            a += v4 * w4; a += v5 * w5; a += v6 * w6; a += v7 * w7;
        }
        for (; j < nb; ++j) {
            int s = __shfl(src, j);
            float ww = __shfl(w, j);
            if (lane < IN_DIM) a += x[s * IN_DIM + lane] * ww;
        }
    }
    a *= dinv[n];
    float acc = b1[lane];
#pragma unroll
    for (int k = 0; k < IN_DIM; ++k) {
        acc += __shfl(a, k) * W1[k * HIDDEN + lane];
    }
    h1[n * HIDDEN + lane] = fmaxf(acc, 0.f);
}

// ---------------- layer 2: aggregate h1 (64 dims) then @W2+b2, relu ----------------
__global__ __launch_bounds__(256) void k_layer2(const float* __restrict__ hin,
                                                const float* __restrict__ dinv,
                                                const int* __restrict__ offs,
                                                const int* __restrict__ deg,
                                                const int* __restrict__ csr_src,
                                                const float* __restrict__ W,
                                                const float* __restrict__ b,
                                                float* __restrict__ hout) {
    __shared__ float sW[HIDDEN * HIDDEN];
    for (int i = threadIdx.x; i < HIDDEN * HIDDEN; i += blockDim.x) sW[i] = W[i];
    __syncthreads();
    int wid = (blockIdx.x * blockDim.x + threadIdx.x) >> 6;
    int lane = threadIdx.x & 63;
    if (wid >= N_NODES) return;
    int n = wid;
    float a = agg64(hin, dinv, csr_src, offs[n], deg[n], lane);
    a *= dinv[n];
    float acc = b[lane];
    for (int k = 0; k < HIDDEN; ++k) {
        acc += __shfl(a, k) * sW[k * HIDDEN + lane];
    }
    hout[n * HIDDEN + lane] = fmaxf(acc, 0.f);
}

// ---------------- layer 3: aggregate h2, pool into graph accumulator ----------------
__global__ __launch_bounds__(256) void k_layer3(const float* __restrict__ hin,
                                                const float* __restrict__ dinv,
                                                const int* __restrict__ offs,
                                                const int* __restrict__ deg,
                                                const int* __restrict__ csr_src,
                                                const int* __restrict__ batch,
                                                float* __restrict__ gpre,
                                                int* __restrict__ gcnt) {
    int wid = (blockIdx.x * blockDim.x + threadIdx.x) >> 6;
    int lane = threadIdx.x & 63;
    if (wid >= N_NODES) return;
    int n = wid;
    float a = agg64(hin, dinv, csr_src, offs[n], deg[n], lane);
    a *= dinv[n];
    int g = batch[n];
    atomicAdd(&gpre[g * HIDDEN + lane], a);
    if (lane == 0) atomicAdd(&gcnt[g], 1);
}

// ---------------- final: pooled @ W3 + cnt*b3, @ Wl + bl, softmax ----------------
__global__ __launch_bounds__(256) void k_final(const float* __restrict__ gpre,
                                               const int* __restrict__ gcnt,
                                               const float* __restrict__ W3,
                                               const float* __restrict__ b3,
                                               const float* __restrict__ Wl,
                                               const float* __restrict__ bl,
                                               float* __restrict__ out) {
    int wid = (blockIdx.x * blockDim.x + threadIdx.x) >> 6;
    int lane = threadIdx.x & 63;
    if (wid >= N_GRAPHS) return;
    float pre = gpre[wid * HIDDEN + lane];
    float cnt = (float)gcnt[wid];
    float emb = cnt * b3[lane];
    for (int k = 0; k < HIDDEN; ++k) {
        emb += __shfl(pre, k) * W3[k * HIDDEN + lane];
    }
    float p0 = emb * Wl[lane * 2 + 0];
    float p1 = emb * Wl[lane * 2 + 1];
    for (int d = 32; d > 0; d >>= 1) {
        p0 += __shfl_xor(p0, d);
        p1 += __shfl_xor(p1, d);
    }
    if (lane == 0) {
        float l0 = p0 + bl[0], l1 = p1 + bl[1];
        float m = fmaxf(l0, l1);
        float e0 = __expf(l0 - m), e1 = __expf(l1 - m);
        float inv = 1.f / (e0 + e1);
        out[wid * 2 + 0] = e0 * inv;
        out[wid * 2 + 1] = e1 * inv;
    }
}

extern "C" void kernel_launch(void* const* d_in, const int* in_sizes, int n_in,
                              void* d_out, int out_size, void* d_ws, size_t ws_size,
                              hipStream_t stream) {
    const float* x = (const float*)d_in[0];
    const int* edge = (const int*)d_in[1];  // [2, E] flattened: row = edge[0:E], col = edge[E:2E]
    const int* batch = (const int*)d_in[2];
    const float* W1 = (const float*)d_in[3];
    const float* b1 = (const float*)d_in[4];
    const float* W2 = (const float*)d_in[5];
    const float* b2 = (const float*)d_in[6];
    const float* W3 = (const float*)d_in[7];
    const float* b3 = (const float*)d_in[8];
    const float* Wl = (const float*)d_in[9];
    const float* bl = (const float*)d_in[10];
    float* out = (float*)d_out;

    const int* row = edge;
    const int* col = edge + N_EDGES;

    // workspace carve-up (256B aligned)
    char* ws = (char*)d_ws;
    size_t off = 0;
    auto alloc = [&](size_t bytes) -> void* {
        void* p = ws + off;
        off = (off + bytes + 255) & ~(size_t)255;
        return p;
    };
    int* deg = (int*)alloc((size_t)N_NODES * 4);
    int* offs = (int*)alloc((size_t)N_NODES * 4);
    int* bsums = (int*)alloc(128 * 4);
    int* cursor = (int*)alloc((size_t)N_NODES * 4);
    float* dinv = (float*)alloc((size_t)N_NODES * 4);
    int* csr_src = (int*)alloc((size_t)N_EDGES * 4);
    float* h1 = (float*)alloc((size_t)N_NODES * HIDDEN * 4);
    float* h2 = (float*)alloc((size_t)N_NODES * HIDDEN * 4);
    float* gpre = (float*)alloc((size_t)N_GRAPHS * HIDDEN * 4);
    int* gcnt = (int*)alloc((size_t)N_GRAPHS * 4);

    hipMemsetAsync(deg, 0, (size_t)N_NODES * 4, stream);
    hipMemsetAsync(cursor, 0, (size_t)N_NODES * 4, stream);
    hipMemsetAsync(gpre, 0, (size_t)N_GRAPHS * HIDDEN * 4, stream);
    hipMemsetAsync(gcnt, 0, (size_t)N_GRAPHS * 4, stream);

    const int EB = (N_EDGES + 255) / 256;
    const int NB1024 = (N_NODES + 1023) / 1024;  // 98

    k_deg<<<EB, 256, 0, stream>>>(col, deg);
    k_scan_block<<<NB1024, 1024, 0, stream>>>(deg, offs, bsums);
    k_scan_top<<<1, 128, 0, stream>>>(bsums, NB1024);
    k_scan_add<<<NB1024, 1024, 0, stream>>>(offs, bsums);
    k_dinv<<<(N_NODES + 255) / 256, 256, 0, stream>>>(deg, dinv);

    const int NCHUNKS = (N_EDGES + CHUNK_EDGES - 1) / CHUNK_EDGES;  // 782
    k_fill<<<NCHUNKS * NRANGES, 256, 0, stream>>>(row, col, offs, cursor, csr_src);

    const int WB = (N_NODES * 64 + 255) / 256;  // one wave per node
    k_layer1<<<WB, 256, 0, stream>>>(x, dinv, offs, deg, csr_src, W1, b1, h1);
    k_layer2<<<WB, 256, 0, stream>>>(h1, dinv, offs, deg, csr_src, W2, b2, h2);
    k_layer3<<<WB, 256, 0, stream>>>(h2, dinv, offs, deg, csr_src, batch, gpre, gcnt);
    k_final<<<(N_GRAPHS * 64 + 255) / 256, 256, 0, stream>>>(gpre, gcnt, W3, b3, Wl, bl, out);
}